// Round 9
// baseline (721.920 us; speedup 1.0000x reference)
//
#include <hip/hip_runtime.h>

// MoE-INR fused megakernel, bf16 MFMA (gfx950). Round 9:
// 128-row blocks (512 blocks): halves per-dispatch weight traffic
// (blocks x 2.2MB) -- the model that fits r3-r8's invariant ~400us is
// latency-bound W-fetch with VGPR-capped outstanding loads, so traffic/CU
// is the lever. 512 threads, launch_bounds(512,2) (spill-free lineage).
// LDS: P+Q at stride 260 = 133.1KB + pred + probs = 137.7KB < usable
// (~140.3KB, proven r4 vs r8). Swapped-operand wgemm (D[feat][batch]),
// ct=8 batch tiles, packed b64 epilogue.

typedef short v8s __attribute__((ext_vector_type(8)));
typedef float v4f __attribute__((ext_vector_type(4)));

#define OMEGA_F 30.0f
#define AST 260   // LDS row stride in bf16 elems (520B = 130 dw; 2-way = free)
#define N_CVT 8

__device__ __forceinline__ float bf2f(unsigned short h) {
  union { unsigned u; float f; } v; v.u = ((unsigned)h) << 16; return v.f;
}
__device__ __forceinline__ unsigned short f2bf(float f) {
  union { float f; unsigned u; } v; v.f = f;
  unsigned r = v.u + 0x7fffu + ((v.u >> 16) & 1u);  // RNE
  return (unsigned short)(r >> 16);
}
__device__ __forceinline__ unsigned pack2(float lo, float hi) {
  return (unsigned)f2bf(lo) | ((unsigned)f2bf(hi) << 16);
}

struct CvtArgs {
  const float* src[N_CVT];
  unsigned     off[N_CVT];
  unsigned     n[N_CVT];   // all divisible by 4
};

typedef float v4fv __attribute__((ext_vector_type(4)));
typedef unsigned short v4u16 __attribute__((ext_vector_type(4)));

__global__ void convert_kernel(CvtArgs a, unsigned short* __restrict__ dst) {
  const int tid = blockIdx.x * blockDim.x + threadIdx.x;
  const int stride = gridDim.x * blockDim.x;
  for (int k = 0; k < N_CVT; k++) {
    const unsigned n4 = a.n[k] >> 2;
    const v4fv* s = (const v4fv*)a.src[k];
    v4u16* d = (v4u16*)(dst + a.off[k]);
    for (unsigned i = tid; i < n4; i += stride) {
      v4fv v = s[i];
      v4u16 o;
      o.x = f2bf(v.x); o.y = f2bf(v.y); o.z = f2bf(v.z); o.w = f2bf(v.w);
      d[i] = o;
    }
  }
}

// ------- swapped-operand wave GEMM (8 waves, 128 batch rows) -------
// OUT[b][oc+o] = act( sum_k A[b][k] * W[o][k] + bias[o] )
// Amat = W rows (global), Bmat = activations (LDS, stride AST).
// D[m=o][n=b]. Wave w covers o in [w*OUT/8,(w+1)*OUT/8), all 128 b (ct=8).
// ACT: 0=sin(30z), 1=relu, 2=relu(z+skip)
template<int K, int OUT, int ACT>
__device__ __forceinline__ void wgemm_s(const unsigned short* A,
                                        unsigned short* OUTP, int oc,
                                        const unsigned short* __restrict__ W,
                                        const float* __restrict__ bias,
                                        const unsigned short* skip) {
  constexpr int RT = OUT / 128;   // 16-feature tiles per wave
  constexpr int KI = K / 32;
  const int lane = threadIdx.x & 63;
  const int wave = threadIdx.x >> 6;
  const int m15  = lane & 15;
  const int q    = lane >> 4;
  const int n0w  = wave * (OUT / 8);
  v4f acc[RT][8];
#pragma unroll
  for (int i = 0; i < RT; i++)
#pragma unroll
    for (int j = 0; j < 8; j++) acc[i][j] = (v4f){0.f, 0.f, 0.f, 0.f};

#pragma unroll
  for (int k0 = 0; k0 < KI; ++k0) {
    v8s af[RT], bf[8];
#pragma unroll
    for (int rt = 0; rt < RT; rt++)
      af[rt] = *(const v8s*)(W + (size_t)(n0w + rt * 16 + m15) * K + k0 * 32 + q * 8);
#pragma unroll
    for (int ct = 0; ct < 8; ct++)
      bf[ct] = *(const v8s*)(A + (ct * 16 + m15) * AST + k0 * 32 + q * 8);
#pragma unroll
    for (int rt = 0; rt < RT; rt++)
#pragma unroll
      for (int ct = 0; ct < 8; ct++)
        acc[rt][ct] = __builtin_amdgcn_mfma_f32_16x16x32_bf16(af[rt], bf[ct], acc[rt][ct], 0, 0, 0);
  }

#pragma unroll
  for (int ct = 0; ct < 8; ct++) {
    const int b = ct * 16 + m15;
#pragma unroll
    for (int rt = 0; rt < RT; rt++) {
      const int o0 = n0w + rt * 16 + q * 4;
      const v4f bv = *(const v4f*)(bias + o0);
      float z[4];
#pragma unroll
      for (int r = 0; r < 4; r++) z[r] = acc[rt][ct][r] + bv[r];
      if (ACT == 2) {
        uint2 sv = *(const uint2*)(skip + b * AST + oc + o0);
        z[0] += bf2f((unsigned short)(sv.x & 0xffffu));
        z[1] += bf2f((unsigned short)(sv.x >> 16));
        z[2] += bf2f((unsigned short)(sv.y & 0xffffu));
        z[3] += bf2f((unsigned short)(sv.y >> 16));
      }
      float o[4];
#pragma unroll
      for (int r = 0; r < 4; r++) {
        if (ACT == 0) o[r] = __sinf(OMEGA_F * z[r]);
        else          o[r] = fmaxf(z[r], 0.f);
      }
      uint2 pk;
      pk.x = pack2(o[0], o[1]);
      pk.y = pack2(o[2], o[3]);
      *(uint2*)(OUTP + b * AST + oc + o0) = pk;
    }
  }
}

// Expert layer 2 fused with final 256->1 dot (swapped operands, 8 waves,
// 128 rows). Wave w covers o2 in [w*32,(w+1)*32); LDS f32 atomics into
// pred[128] (barrier-ordered with readers).
__device__ __forceinline__ void wexpert2_s(const unsigned short* A,
                                           const unsigned short* __restrict__ W,
                                           const float* __restrict__ bias,
                                           const float* __restrict__ wfin,
                                           float* pred /* [128] */) {
  const int lane = threadIdx.x & 63;
  const int wave = threadIdx.x >> 6;
  const int m15  = lane & 15;
  const int q    = lane >> 4;
  const int n0w  = wave * 32;
  v4f acc[2][8];
#pragma unroll
  for (int i = 0; i < 2; i++)
#pragma unroll
    for (int j = 0; j < 8; j++) acc[i][j] = (v4f){0.f, 0.f, 0.f, 0.f};

#pragma unroll
  for (int k0 = 0; k0 < 8; ++k0) {
    v8s af[2], bf[8];
#pragma unroll
    for (int rt = 0; rt < 2; rt++)
      af[rt] = *(const v8s*)(W + (size_t)(n0w + rt * 16 + m15) * 256 + k0 * 32 + q * 8);
#pragma unroll
    for (int ct = 0; ct < 8; ct++)
      bf[ct] = *(const v8s*)(A + (ct * 16 + m15) * AST + k0 * 32 + q * 8);
#pragma unroll
    for (int rt = 0; rt < 2; rt++)
#pragma unroll
      for (int ct = 0; ct < 8; ct++)
        acc[rt][ct] = __builtin_amdgcn_mfma_f32_16x16x32_bf16(af[rt], bf[ct], acc[rt][ct], 0, 0, 0);
  }

  float p[8];
#pragma unroll
  for (int ct = 0; ct < 8; ct++) p[ct] = 0.f;
#pragma unroll
  for (int rt = 0; rt < 2; rt++) {
    const int o0 = n0w + rt * 16 + q * 4;
    const v4f bv = *(const v4f*)(bias + o0);
    const v4f wv = *(const v4f*)(wfin + o0);
#pragma unroll
    for (int ct = 0; ct < 8; ct++)
#pragma unroll
      for (int r = 0; r < 4; r++)
        p[ct] += __sinf(OMEGA_F * (acc[rt][ct][r] + bv[r])) * wv[r];
  }
#pragma unroll
  for (int ct = 0; ct < 8; ct++) {
    float v = p[ct];
    v += __shfl_xor(v, 16);
    v += __shfl_xor(v, 32);
    if (q == 0) atomicAdd(&pred[ct * 16 + m15], v);
  }
}

__global__ __launch_bounds__(512, 2) void moe_inr_kernel(
    const float* __restrict__ x,
    const unsigned short* __restrict__ es1w, const float* __restrict__ es1b,
    const unsigned short* __restrict__ es2w, const float* __restrict__ es2b,
    const unsigned short* __restrict__ rf1w, const float* __restrict__ rf1b,
    const unsigned short* __restrict__ rf2w, const float* __restrict__ rf2b,
    const unsigned short* __restrict__ rf3w, const float* __restrict__ rf3b,
    const float* __restrict__ ps1w,          const float* __restrict__ ps1b,
    const unsigned short* __restrict__ ps2w, const float* __restrict__ ps2b,
    const float* __restrict__ gw,            const float* __restrict__ gb,
    const unsigned short* __restrict__ xs1w, const float* __restrict__ xs1b,
    const unsigned short* __restrict__ xs2w, const float* __restrict__ xs2b,
    const float* __restrict__ xfw,           const float* __restrict__ xfb,
    float* __restrict__ out) {
  __shared__ __align__(16) unsigned short P[128 * AST];
  __shared__ __align__(16) unsigned short Q[128 * AST];
  __shared__ float probs[128 * 8];
  __shared__ float pred[128];

  const int t  = threadIdx.x;
  const int r0 = blockIdx.x * 128;
  float yacc = 0.f;  // live in t<128 threads only

  // Stage 0: positional encoding in f32 -> P[b][0..64)
  {
    const int row = t & 127, c = t >> 7;
    const float xv = x[(r0 + row) * 4 + c];
    const float PIf = 3.14159265358979f;
#pragma unroll
    for (int j = 0; j < 8; j++) {
      float ang = xv * (PIf * (float)(1 << j));
      P[row * AST + c * 16 + j]     = f2bf(__sinf(ang));
      P[row * AST + c * 16 + 8 + j] = f2bf(__cosf(ang));
    }
  }
  __syncthreads();
  wgemm_s<64, 128, 0>(P, P, 64, es1w, es1b, nullptr);       // h1 -> P[64,192)
  __syncthreads();
  wgemm_s<128, 256, 0>(P + 64, Q, 0, es2w, es2b, nullptr);  // h  -> Q[0,256)
  __syncthreads();
  wgemm_s<256, 128, 1>(Q, P, 0, rf1w, rf1b, nullptr);       // r1 -> P[0,128)
  __syncthreads();
  wgemm_s<128, 128, 1>(P, P, 128, rf2w, rf2b, nullptr);     // r2 -> P[128,256)
  __syncthreads();
  wgemm_s<128, 256, 2>(P + 128, Q, 0, rf3w, rf3b, Q);       // enc_feat -> Q
  __syncthreads();
  // pol_s1 (K=4) in f32: pf1 -> P[0,128). 512 threads: 32 outputs each.
  {
    const int row = t & 127, g = t >> 7;
    const float xv0 = x[(r0 + row) * 4 + 0];
    const float xv1 = x[(r0 + row) * 4 + 1];
    const float xv2 = x[(r0 + row) * 4 + 2];
    const float xv3 = x[(r0 + row) * 4 + 3];
    for (int i = 0; i < 32; i++) {
      int o = g * 32 + i;
      float z = xv0 * ps1w[o * 4 + 0] + xv1 * ps1w[o * 4 + 1] +
                xv2 * ps1w[o * 4 + 2] + xv3 * ps1w[o * 4 + 3] + ps1b[o];
      P[row * AST + o] = f2bf(__sinf(OMEGA_F * z));
    }
  }
  __syncthreads();
  wgemm_s<128, 128, 0>(P, P, 128, ps2w, ps2b, nullptr);     // pf -> P[128,256)
  __syncthreads();
  // gate (f32 weights): 4 partial-threads per row (96 k each)
  {
    const int row = t >> 2, pp = t & 3;
    float lg[7];
#pragma unroll
    for (int j = 0; j < 7; j++) {
      float s = 0.f;
      for (int kk = pp * 96; kk < pp * 96 + 96; ++kk) {
        float v = (kk < 256) ? bf2f(Q[row * AST + kk])
                             : bf2f(P[row * AST + 128 + (kk - 256)]);
        s += v * gw[j * 384 + kk];
      }
      s += __shfl_xor(s, 1);
      s += __shfl_xor(s, 2);
      lg[j] = s;
    }
    if (pp == 0) {
#pragma unroll
      for (int j = 0; j < 7; j++) probs[row * 8 + j] = lg[j] + gb[j];
    }
  }
  __syncthreads();
  if (t < 128) {  // softmax over 7 + zero pred
    float m = probs[t * 8];
#pragma unroll
    for (int j = 1; j < 7; j++) m = fmaxf(m, probs[t * 8 + j]);
    float s = 0.f, e[7];
#pragma unroll
    for (int j = 0; j < 7; j++) { e[j] = __expf(probs[t * 8 + j] - m); s += e[j]; }
    float inv = 1.f / s;
#pragma unroll
    for (int j = 0; j < 7; j++) probs[t * 8 + j] = e[j] * inv;
    pred[t] = 0.f;
  }
  // experts: enc_feat stays in Q; e1 -> P[0,256); e2+final via LDS atomics
  for (int ex = 0; ex < 7; ++ex) {
    __syncthreads();
    wgemm_s<256, 256, 0>(Q, P, 0, xs1w + ex * 65536, xs1b + ex * 256, nullptr);
    __syncthreads();
    wexpert2_s(P, xs2w + ex * 65536, xs2b + ex * 256, xfw + ex * 256, pred);
    __syncthreads();
    if (t < 128) {
      yacc += (pred[t] + xfb[ex]) * probs[t * 8 + ex];
      pred[t] = 0.f;  // two barriers before next expert's atomics
    }
  }
  __syncthreads();
  if (t < 128) out[r0 + t] = yacc;
}

extern "C" void kernel_launch(void* const* d_in, const int* in_sizes, int n_in,
                              void* d_out, int out_size, void* d_ws, size_t ws_size,
                              hipStream_t stream) {
  (void)out_size; (void)n_in; (void)ws_size;
  const int idx[N_CVT] = {1, 3, 5, 7, 9, 13, 17, 19};
  unsigned off[N_CVT], cur = 0;
  CvtArgs a;
  for (int i = 0; i < N_CVT; i++) {
    off[i] = cur;
    a.src[i] = (const float*)d_in[idx[i]];
    a.off[i] = cur;
    a.n[i]   = (unsigned)in_sizes[idx[i]];
    cur += ((unsigned)in_sizes[idx[i]] + 7u) & ~7u;  // 16B-align each array
  }
  unsigned short* dst = (unsigned short*)d_ws;
  hipLaunchKernelGGL(convert_kernel, dim3(512), dim3(256), 0, stream, a, dst);
  hipLaunchKernelGGL(moe_inr_kernel, dim3(65536 / 128), dim3(512), 0, stream,
      (const float*)d_in[0],
      dst + off[0], (const float*)d_in[2],
      dst + off[1], (const float*)d_in[4],
      dst + off[2], (const float*)d_in[6],
      dst + off[3], (const float*)d_in[8],
      dst + off[4], (const float*)d_in[10],
      (const float*)d_in[11], (const float*)d_in[12],
      dst + off[5], (const float*)d_in[14],
      (const float*)d_in[15], (const float*)d_in[16],
      dst + off[6], (const float*)d_in[18],
      dst + off[7], (const float*)d_in[20],
      (const float*)d_in[21], (const float*)d_in[22],
      (float*)d_out);
}